// Round 1
// baseline (232.057 us; speedup 1.0000x reference)
//
#include <hip/hip_runtime.h>

// Problem constants (B,T,D,U) = (64, 2048, 256, 256)
#define B 64
#define T 2048
#define D 256
#define U 256
#define NC 16          // t-chunks for the accumulation pass
#define TC (T / NC)    // 128 t per chunk

// ws layout (floats):
//   [0, 256)                         wv = W @ v
//   [256, 256 + B*T)                 scores -> probabilities (in place)
//   [256 + B*T, + B*NC*D)            partial accumulations
// total = 256 + 131072 + 262144 floats ~= 1.54 MB

// ---------------------------------------------------------------- wv = W @ v
__global__ __launch_bounds__(256) void k_wv(const float* __restrict__ W,
                                            const float* __restrict__ v,
                                            float* __restrict__ wv) {
    int d = threadIdx.x;
    const float4* Wr = (const float4*)(W + d * U);
    const float4* v4 = (const float4*)v;
    float acc = 0.f;
    #pragma unroll 4
    for (int u = 0; u < U / 4; ++u) {
        float4 w = Wr[u];
        float4 vv = v4[u];
        acc += w.x * vv.x + w.y * vv.y + w.z * vv.z + w.w * vv.w;
    }
    wv[d] = acc;
}

// ------------------------------------------- scores[b,t] = x[b,t,:] . wv
// One wave per row (row = b*T + t), 4 rows per wave, 4 waves per block.
__global__ __launch_bounds__(256) void k_scores(const float* __restrict__ x,
                                                const float* __restrict__ wv,
                                                float* __restrict__ scores) {
    int lane = threadIdx.x & 63;
    int wave = threadIdx.x >> 6;
    long long rowbase = (long long)blockIdx.x * 16 + wave * 4;
    float4 w4 = ((const float4*)wv)[lane];   // loaded once per wave, reused 4 rows
    #pragma unroll
    for (int i = 0; i < 4; ++i) {
        long long r = rowbase + i;
        float4 xv = ((const float4*)(x + r * D))[lane];
        float s = xv.x * w4.x + xv.y * w4.y + xv.z * w4.z + xv.w * w4.w;
        #pragma unroll
        for (int off = 32; off > 0; off >>= 1)
            s += __shfl_down(s, off, 64);
        if (lane == 0) scores[r] = s;
    }
}

// ------------------------------------------- softmax over t, one block per b
__global__ __launch_bounds__(256) void k_softmax(float* __restrict__ scores) {
    int b = blockIdx.x;
    float* s = scores + (long long)b * T;
    int lane = threadIdx.x & 63, wid = threadIdx.x >> 6;
    float loc[T / 256];
    float mx = -1e30f;
    #pragma unroll
    for (int k = 0; k < T / 256; ++k) {
        loc[k] = s[threadIdx.x + k * 256];
        mx = fmaxf(mx, loc[k]);
    }
    #pragma unroll
    for (int off = 32; off > 0; off >>= 1)
        mx = fmaxf(mx, __shfl_down(mx, off, 64));
    __shared__ float sm[4];
    __shared__ float bc[2];
    if (lane == 0) sm[wid] = mx;
    __syncthreads();
    if (threadIdx.x == 0)
        bc[0] = fmaxf(fmaxf(sm[0], sm[1]), fmaxf(sm[2], sm[3]));
    __syncthreads();
    mx = bc[0];
    float sum = 0.f;
    #pragma unroll
    for (int k = 0; k < T / 256; ++k) {
        loc[k] = __expf(loc[k] - mx);
        sum += loc[k];
    }
    #pragma unroll
    for (int off = 32; off > 0; off >>= 1)
        sum += __shfl_down(sum, off, 64);
    __syncthreads();   // protect sm reuse
    if (lane == 0) sm[wid] = sum;
    __syncthreads();
    if (threadIdx.x == 0)
        bc[1] = 1.f / (sm[0] + sm[1] + sm[2] + sm[3]);
    __syncthreads();
    float inv = bc[1];
    #pragma unroll
    for (int k = 0; k < T / 256; ++k)
        s[threadIdx.x + k * 256] = loc[k] * inv;
}

// ---------------------- partial[b,c,:] = sum_{t in chunk c} p[b,t]*x[b,t,:]
// Block = (b, c). 4 waves each take t = q mod 4; lanes cover D via float4.
__global__ __launch_bounds__(256) void k_accum(const float* __restrict__ x,
                                               const float* __restrict__ p,
                                               float* __restrict__ partial) {
    int b = blockIdx.x >> 4;          // NC == 16
    int c = blockIdx.x & (NC - 1);
    int l = threadIdx.x & 63;
    int q = threadIdx.x >> 6;         // wave-uniform
    const float4* xb = (const float4*)(x + ((long long)b * T + (long long)c * TC) * D);
    const float* pb = p + (long long)b * T + c * TC;
    float4 acc = {0.f, 0.f, 0.f, 0.f};
    for (int t = q; t < TC; t += 4) {
        float pv = pb[t];                       // wave-uniform -> scalar load
        float4 xv = xb[(long long)t * 64 + l];  // coalesced 1KB per wave
        acc.x = fmaf(pv, xv.x, acc.x);
        acc.y = fmaf(pv, xv.y, acc.y);
        acc.z = fmaf(pv, xv.z, acc.z);
        acc.w = fmaf(pv, xv.w, acc.w);
    }
    __shared__ float4 red[4][64];
    red[q][l] = acc;
    __syncthreads();
    if (q == 0) {
        float4 a0 = red[0][l], a1 = red[1][l], a2 = red[2][l], a3 = red[3][l];
        float4 r;
        r.x = a0.x + a1.x + a2.x + a3.x;
        r.y = a0.y + a1.y + a2.y + a3.y;
        r.z = a0.z + a1.z + a2.z + a3.z;
        r.w = a0.w + a1.w + a2.w + a3.w;
        ((float4*)(partial + (long long)blockIdx.x * D))[l] = r;
    }
}

// ------------------------------------------- out[b,:] = sum_c partial[b,c,:]
__global__ __launch_bounds__(256) void k_reduce(const float* __restrict__ partial,
                                               float* __restrict__ out) {
    int b = blockIdx.x;
    int d = threadIdx.x;
    float acc = 0.f;
    #pragma unroll
    for (int c = 0; c < NC; ++c)
        acc += partial[((long long)(b * NC + c)) * D + d];
    out[(long long)b * D + d] = acc;
}

extern "C" void kernel_launch(void* const* d_in, const int* in_sizes, int n_in,
                              void* d_out, int out_size, void* d_ws, size_t ws_size,
                              hipStream_t stream) {
    // inputs: x, g, W, Wg, b, v  -- g/Wg/b provably cancel in softmax
    const float* x = (const float*)d_in[0];
    const float* W = (const float*)d_in[2];
    const float* v = (const float*)d_in[5];
    float* ws = (float*)d_ws;
    float* wv      = ws;
    float* scores  = ws + 256;
    float* partial = ws + 256 + B * T;
    float* out = (float*)d_out;

    k_wv<<<1, 256, 0, stream>>>(W, v, wv);
    k_scores<<<(B * T) / 16, 256, 0, stream>>>(x, wv, scores);
    k_softmax<<<B, 256, 0, stream>>>(scores);
    k_accum<<<B * NC, 256, 0, stream>>>(x, scores, partial);
    k_reduce<<<B, 256, 0, stream>>>(partial, out);
}

// Round 2
// 211.190 us; speedup vs baseline: 1.0988x; 1.0988x over previous
//
#include <hip/hip_runtime.h>

// Problem constants (B,T,D,U) = (64, 2048, 256, 256)
#define B 64
#define T 2048
#define D 256
#define U 256
#define NC 16          // t-chunks (blocks per batch)
#define TC (T / NC)    // 128 rows per chunk

// ws layout (floats):
//   [0, 256)                  wv = W @ v
//   [256, 256+B*NC)           chunk max m_c
//   [.., +B*NC)               chunk sum l_c
//   [.., +B*NC*D)             chunk weighted accum O_c
#define WS_WV   0
#define WS_M    (WS_WV + 256)
#define WS_L    (WS_M + B * NC)
#define WS_O    (WS_L + B * NC)

// ---------------------------------------------------------------- wv = W @ v
__global__ __launch_bounds__(256) void k_wv(const float* __restrict__ W,
                                            const float* __restrict__ v,
                                            float* __restrict__ wv) {
    int d = threadIdx.x;
    const float4* Wr = (const float4*)(W + d * U);
    const float4* v4 = (const float4*)v;
    float acc = 0.f;
    #pragma unroll 4
    for (int u = 0; u < U / 4; ++u) {
        float4 w = Wr[u];
        float4 vv = v4[u];
        acc += w.x * vv.x + w.y * vv.y + w.z * vv.z + w.w * vv.w;
    }
    wv[d] = acc;
}

// ------------- fused: scores + online softmax + weighted accum, 1 pass over x
// Block = (b, c). 4 waves; wave q handles rows t = q, q+4, ... of the chunk.
// Each wave keeps flash-style running (m, l, acc[4]) in registers; x is read
// ONCE and reused for both the dot product and the weighted accumulation.
__global__ __launch_bounds__(256) void k_fused(const float* __restrict__ x,
                                               const float* __restrict__ wv,
                                               float* __restrict__ pM,
                                               float* __restrict__ pL,
                                               float* __restrict__ pO) {
    int b = blockIdx.x >> 4;          // NC == 16
    int c = blockIdx.x & (NC - 1);
    int l = threadIdx.x & 63;
    int q = threadIdx.x >> 6;         // wave-uniform

    float4 w4 = ((const float4*)wv)[l];
    const float4* xb =
        (const float4*)(x + ((long long)b * T + (long long)c * TC) * D);

    float m = -1e30f, lsum = 0.f;
    float4 acc = {0.f, 0.f, 0.f, 0.f};

    for (int t = q; t < TC; t += 4) {
        float4 xv = xb[(long long)t * 64 + l];   // coalesced 1 KB per wave
        float s = xv.x * w4.x + xv.y * w4.y + xv.z * w4.z + xv.w * w4.w;
        #pragma unroll
        for (int off = 1; off < 64; off <<= 1)   // butterfly: all lanes get sum
            s += __shfl_xor(s, off, 64);
        float m_new = fmaxf(m, s);
        float alpha = __expf(m - m_new);         // exp(-1e30)=0 handles first iter
        float p = __expf(s - m_new);
        lsum = lsum * alpha + p;
        acc.x = fmaf(p, xv.x, acc.x * alpha);
        acc.y = fmaf(p, xv.y, acc.y * alpha);
        acc.z = fmaf(p, xv.z, acc.z * alpha);
        acc.w = fmaf(p, xv.w, acc.w * alpha);
        m = m_new;
    }

    // cross-wave combine via LDS
    __shared__ float4 redO[4][64];
    __shared__ float redM[4], redL[4];
    redO[q][l] = acc;
    if (l == 0) { redM[q] = m; redL[q] = lsum; }
    __syncthreads();
    if (q == 0) {
        float M = fmaxf(fmaxf(redM[0], redM[1]), fmaxf(redM[2], redM[3]));
        float e0 = __expf(redM[0] - M), e1 = __expf(redM[1] - M);
        float e2 = __expf(redM[2] - M), e3 = __expf(redM[3] - M);
        float4 a0 = redO[0][l], a1 = redO[1][l], a2 = redO[2][l], a3 = redO[3][l];
        float4 r;
        r.x = a0.x * e0 + a1.x * e1 + a2.x * e2 + a3.x * e3;
        r.y = a0.y * e0 + a1.y * e1 + a2.y * e2 + a3.y * e3;
        r.z = a0.z * e0 + a1.z * e1 + a2.z * e2 + a3.z * e3;
        r.w = a0.w * e0 + a1.w * e1 + a2.w * e2 + a3.w * e3;
        ((float4*)(pO + (long long)blockIdx.x * D))[l] = r;
        if (l == 0) {
            pM[blockIdx.x] = M;
            pL[blockIdx.x] = redL[0] * e0 + redL[1] * e1 + redL[2] * e2 + redL[3] * e3;
        }
    }
}

// ---------------- combine NC chunk-partials per batch -> out[b,:]
__global__ __launch_bounds__(256) void k_combine(const float* __restrict__ pM,
                                                 const float* __restrict__ pL,
                                                 const float* __restrict__ pO,
                                                 float* __restrict__ out) {
    int b = blockIdx.x;
    int d = threadIdx.x;
    // global max over chunks (redundant per thread; scalar broadcast loads)
    float M = -1e30f;
    #pragma unroll
    for (int c = 0; c < NC; ++c)
        M = fmaxf(M, pM[b * NC + c]);
    float denom = 0.f, acc = 0.f;
    #pragma unroll
    for (int c = 0; c < NC; ++c) {
        float e = __expf(pM[b * NC + c] - M);
        denom += e * pL[b * NC + c];
        acc = fmaf(e, pO[((long long)(b * NC + c)) * D + d], acc);
    }
    out[(long long)b * D + d] = acc / denom;
}

extern "C" void kernel_launch(void* const* d_in, const int* in_sizes, int n_in,
                              void* d_out, int out_size, void* d_ws, size_t ws_size,
                              hipStream_t stream) {
    // inputs: x, g, W, Wg, b, v  -- g/Wg/b cancel under softmax shift-invariance
    const float* x = (const float*)d_in[0];
    const float* W = (const float*)d_in[2];
    const float* v = (const float*)d_in[5];
    float* ws = (float*)d_ws;
    float* wv = ws + WS_WV;
    float* pM = ws + WS_M;
    float* pL = ws + WS_L;
    float* pO = ws + WS_O;
    float* out = (float*)d_out;

    k_wv<<<1, 256, 0, stream>>>(W, v, wv);
    k_fused<<<B * NC, 256, 0, stream>>>(x, wv, pM, pL, pO);
    k_combine<<<B, 256, 0, stream>>>(pM, pL, pO, out);
}